// Round 5
// baseline (1173.752 us; speedup 1.0000x reference)
//
#include <hip/hip_runtime.h>
#include <math.h>

#define N_NODES 50000
#define E_EDGES 800000
#define D_FEAT  64
#define C_CH    3
#define H_HID   8
#define OUT_F   128
#define CD      192              // C*D
#define NTILES  (N_NODES / 16)   // 3125 exact
#define BK      32               // nodes per bucket
#define NBUCK   ((N_NODES + BK - 1) / BK)   // 1563

typedef _Float16 half8 __attribute__((ext_vector_type(8)));
typedef _Float16 half4 __attribute__((ext_vector_type(4)));
typedef float f32x4 __attribute__((ext_vector_type(4)));

__device__ __forceinline__ float lrelu(float v) { return v >= 0.f ? v : 0.01f * v; }

// --- K1: histogram of dst buckets -------------------------------------------
__global__ __launch_bounds__(256) void k_bhist(
    const int* __restrict__ ei, int* __restrict__ counts)
{
    int e = blockIdx.x * 256 + threadIdx.x;      // grid covers E exactly
    atomicAdd(counts + (ei[E_EDGES + e] >> 5), 1);
}

// --- K2: exclusive scan of 1563 bucket counts (single block) ----------------
__global__ __launch_bounds__(256) void k_bscan(
    const int* __restrict__ counts, int* __restrict__ offsets)
{
    __shared__ int s[256];
    __shared__ int carry_s;
    int tid = threadIdx.x;
    if (tid == 0) carry_s = 0;
    __syncthreads();
    for (int chunk = 0; chunk < (NBUCK + 255) / 256; ++chunk) {
        int i = chunk * 256 + tid;
        int vv = (i < NBUCK) ? counts[i] : 0;
        s[tid] = vv;
        __syncthreads();
        for (int off = 1; off < 256; off <<= 1) {
            int t = (tid >= off) ? s[tid - off] : 0;
            __syncthreads();
            s[tid] += t;
            __syncthreads();
        }
        int carry = carry_s;
        if (i < NBUCK) offsets[i] = carry + s[tid] - vv;   // exclusive
        __syncthreads();
        if (tid == 0) carry_s += s[255];
        __syncthreads();
    }
}

// --- K3: edge MLP + append into bucket region -------------------------------
// record = {w0, w1, w2, bits(src | dst_local<<16)}; offsets become bucket ends
__global__ __launch_bounds__(256) void k_bplace(
    const int* __restrict__ ei, const float* __restrict__ ea,
    const float* __restrict__ w1, const float* __restrict__ b1,
    const float* __restrict__ w2, const float* __restrict__ b2,
    int* __restrict__ offsets, float4* __restrict__ sorted)
{
    int e = blockIdx.x * 256 + threadIdx.x;
    int src = ei[e];
    int dst = ei[E_EDGES + e];
    float a = ea[e];
    float wc[C_CH];
#pragma unroll
    for (int c = 0; c < C_CH; ++c) {
        float s = 0.f;
#pragma unroll
        for (int h = 0; h < H_HID; ++h) {
            float t = fmaf(a, w1[c * H_HID + h], b1[c * H_HID + h]);
            t = (t >= 0.f) ? t : 0.01f * t;               // leaky_relu
            s = fmaf(t, w2[c * H_HID + h], s);
        }
        s += b2[c];
        wc[c] = (s > 0.f) ? s : expm1f(s);                // elu
    }
    int pos = atomicAdd(offsets + (dst >> 5), 1);
    unsigned sd = (unsigned)src | ((unsigned)(dst & 31) << 16);
    sorted[pos] = make_float4(wc[0], wc[1], wc[2], __uint_as_float(sd));
}

// --- K4: per-bucket LDS-atomic accumulate + residual -> v[N][192] f16 -------
__global__ __launch_bounds__(256) void k_bagg(
    const float4* __restrict__ sorted, const int* __restrict__ endoff,
    const float* __restrict__ x, const float* __restrict__ eps,
    _Float16* __restrict__ v)
{
    __shared__ float acc[BK][CD];        // 24576 B -> 6 blocks/CU

    const int b    = blockIdx.x;
    const int tid  = threadIdx.x;
    const int lane = tid & 63;
    const int wid  = tid >> 6;

    // zero acc (1536 float4)
    f32x4 z = {0.f, 0.f, 0.f, 0.f};
    for (int i = tid; i < BK * CD / 4; i += 256)
        ((f32x4*)&acc[0][0])[i] = z;
    __syncthreads();

    const int start = b ? endoff[b - 1] : 0;
    const int end   = endoff[b];

    // per-wave strided edge loop; iterations independent (compiler pipelines)
    for (int i = start + wid; i < end; i += 4) {
        float4 r = sorted[i];
        unsigned sd = __float_as_uint(r.w);
        int src = sd & 0xFFFF;
        int dl  = (sd >> 16) & 31;
        float xj = x[(size_t)src * D_FEAT + lane];
        atomicAdd(&acc[dl][lane],       r.x * xj);
        atomicAdd(&acc[dl][64 + lane],  r.y * xj);
        atomicAdd(&acc[dl][128 + lane], r.z * xj);
    }
    __syncthreads();

    // v[n][k] = acc + (1+eps_c) * x ; vectorized 4-wide
    const float e0 = 1.f + eps[0], e1 = 1.f + eps[1], e2 = 1.f + eps[2];
    for (int idx = tid; idx < BK * (CD / 4); idx += 256) {   // 6 iters
        int nl = idx / (CD / 4);
        int k  = (idx % (CD / 4)) * 4;
        int n  = b * BK + nl;
        if (n < N_NODES) {
            int c = k >> 6, d = k & 63;
            float ec = (c == 0) ? e0 : (c == 1 ? e1 : e2);
            const float* xp = x + (size_t)n * D_FEAT + d;
            float4 xv = *(const float4*)xp;
            float* ap = &acc[nl][k];
            half4 h;
            h[0] = (_Float16)(ap[0] + ec * xv.x);
            h[1] = (_Float16)(ap[1] + ec * xv.y);
            h[2] = (_Float16)(ap[2] + ec * xv.z);
            h[3] = (_Float16)(ap[3] + ec * xv.w);
            *(half4*)(v + (size_t)n * CD + k) = h;
        }
    }
}

// --- K5: MLP1(lrelu) + MLP2 via f16 MFMA ------------------------------------
__global__ __launch_bounds__(256) void k_mlp(
    const _Float16* __restrict__ v,
    const float* __restrict__ nw1, const float* __restrict__ nb1,
    const float* __restrict__ nw2, const float* __restrict__ nb2,
    float* __restrict__ out)
{
    __shared__ _Float16 vtile[16][CD + 8];     // stride 400B (16B mult)
    __shared__ _Float16 htile[16][OUT_F + 8];  // stride 272B (16B mult)

    const int tid  = threadIdx.x;
    const int lane = tid & 63;
    const int wid  = tid >> 6;
    const int arow = lane & 15;
    const int kg   = lane >> 4;
    const int o0   = wid * 32;

    half8 w1f[6][2], w2f[4][2];
#pragma unroll
    for (int kk = 0; kk < 6; ++kk)
#pragma unroll
        for (int nt = 0; nt < 2; ++nt) {
            half8 f;
            int colb = o0 + nt * 16 + arow;
            int kb = kk * 32 + kg * 8;
#pragma unroll
            for (int j = 0; j < 8; ++j)
                f[j] = (_Float16)nw1[(size_t)(kb + j) * OUT_F + colb];
            w1f[kk][nt] = f;
        }
#pragma unroll
    for (int kk = 0; kk < 4; ++kk)
#pragma unroll
        for (int nt = 0; nt < 2; ++nt) {
            half8 f;
            int colb = o0 + nt * 16 + arow;
            int kb = kk * 32 + kg * 8;
#pragma unroll
            for (int j = 0; j < 8; ++j)
                f[j] = (_Float16)nw2[(size_t)(kb + j) * OUT_F + colb];
            w2f[kk][nt] = f;
        }

    const float b1a = nb1[o0 + arow],      b1b = nb1[o0 + 16 + arow];
    const float b2a = nb2[o0 + arow],      b2b = nb2[o0 + 16 + arow];

    for (int t = blockIdx.x; t < NTILES; t += gridDim.x) {
        const int nb16 = t * 16;
        __syncthreads();

        for (int i = tid; i < 16 * (CD / 8); i += 256) {    // 384 chunks
            int row = i / (CD / 8), c8 = i % (CD / 8);
            *(half8*)&vtile[row][c8 * 8] =
                *(const half8*)(v + (size_t)(nb16 + row) * CD + c8 * 8);
        }
        __syncthreads();

        f32x4 acc0 = {0.f, 0.f, 0.f, 0.f}, acc1 = {0.f, 0.f, 0.f, 0.f};
#pragma unroll
        for (int kk = 0; kk < 6; ++kk) {
            half8 a = *(const half8*)&vtile[arow][kk * 32 + kg * 8];
            acc0 = __builtin_amdgcn_mfma_f32_16x16x32_f16(a, w1f[kk][0], acc0, 0, 0, 0);
            acc1 = __builtin_amdgcn_mfma_f32_16x16x32_f16(a, w1f[kk][1], acc1, 0, 0, 0);
        }
#pragma unroll
        for (int r = 0; r < 4; ++r) {
            int hr = kg * 4 + r;
            htile[hr][o0 + arow]      = (_Float16)lrelu(acc0[r] + b1a);
            htile[hr][o0 + 16 + arow] = (_Float16)lrelu(acc1[r] + b1b);
        }
        __syncthreads();

        f32x4 c0 = {0.f, 0.f, 0.f, 0.f}, c1 = {0.f, 0.f, 0.f, 0.f};
#pragma unroll
        for (int kk = 0; kk < 4; ++kk) {
            half8 a = *(const half8*)&htile[arow][kk * 32 + kg * 8];
            c0 = __builtin_amdgcn_mfma_f32_16x16x32_f16(a, w2f[kk][0], c0, 0, 0, 0);
            c1 = __builtin_amdgcn_mfma_f32_16x16x32_f16(a, w2f[kk][1], c1, 0, 0, 0);
        }
#pragma unroll
        for (int r = 0; r < 4; ++r) {
            size_t n = (size_t)(nb16 + kg * 4 + r);
            out[n * OUT_F + o0 + arow]      = c0[r] + b2a;
            out[n * OUT_F + o0 + 16 + arow] = c1[r] + b2b;
        }
    }
}

extern "C" void kernel_launch(void* const* d_in, const int* in_sizes, int n_in,
                              void* d_out, int out_size, void* d_ws, size_t ws_size,
                              hipStream_t stream)
{
    const float* x    = (const float*)d_in[0];
    const int*   ei   = (const int*)  d_in[1];
    const float* ea   = (const float*)d_in[2];
    const float* w1   = (const float*)d_in[3];
    const float* b1   = (const float*)d_in[4];
    const float* w2   = (const float*)d_in[5];
    const float* b2   = (const float*)d_in[6];
    const float* eps  = (const float*)d_in[7];
    const float* nw1  = (const float*)d_in[8];
    const float* nb1  = (const float*)d_in[9];
    const float* nw2  = (const float*)d_in[10];
    const float* nb2  = (const float*)d_in[11];
    float* out = (float*)d_out;

    // workspace layout
    char* ws = (char*)d_ws;
    int*       counts    = (int*)    (ws + 0);               // 6.3 KB
    int*       offsets   = (int*)    (ws + (64 << 10));      // 6.3 KB
    float4*    sorted    = (float4*) (ws + (1 << 20));       // 12.8 MB
    _Float16*  v         = (_Float16*)(ws + (16u << 20));    // 19.2 MB

    hipMemsetAsync(counts, 0, NBUCK * sizeof(int), stream);

    k_bhist  <<<E_EDGES / 256, 256, 0, stream>>>(ei, counts);
    k_bscan  <<<1,             256, 0, stream>>>(counts, offsets);
    k_bplace <<<E_EDGES / 256, 256, 0, stream>>>(ei, ea, w1, b1, w2, b2, offsets, sorted);
    k_bagg   <<<NBUCK,         256, 0, stream>>>(sorted, offsets, x, eps, v);
    k_mlp    <<<768,           256, 0, stream>>>(v, nw1, nb1, nw2, nb2, out);
}

// Round 6
// 181.761 us; speedup vs baseline: 6.4577x; 6.4577x over previous
//
#include <hip/hip_runtime.h>
#include <math.h>

#define N_NODES 50000
#define E_EDGES 800000
#define D_FEAT  64
#define C_CH    3
#define H_HID   8
#define OUT_F   128
#define CD      192              // C*D
#define NTILES  (N_NODES / 16)   // 3125 exact
#define NBLK_SCAN ((N_NODES + 255) / 256)   // 196

typedef _Float16 half8 __attribute__((ext_vector_type(8)));
typedef float f32x4 __attribute__((ext_vector_type(4)));

__device__ __forceinline__ float lrelu(float v) { return v >= 0.f ? v : 0.01f * v; }

// --- K1: histogram of dst ---------------------------------------------------
__global__ __launch_bounds__(256) void k_hist(
    const int* __restrict__ ei, int* __restrict__ counts)
{
    int e = blockIdx.x * 256 + threadIdx.x;      // grid covers E exactly
    atomicAdd(counts + ei[E_EDGES + e], 1);
}

// --- K2a: per-block sums of counts ------------------------------------------
__global__ __launch_bounds__(256) void k_blocksum(
    const int* __restrict__ counts, int* __restrict__ blocksums)
{
    __shared__ int s[256];
    int i = blockIdx.x * 256 + threadIdx.x;
    s[threadIdx.x] = (i < N_NODES) ? counts[i] : 0;
    __syncthreads();
    for (int off = 128; off >= 1; off >>= 1) {
        if (threadIdx.x < off) s[threadIdx.x] += s[threadIdx.x + off];
        __syncthreads();
    }
    if (threadIdx.x == 0) blocksums[blockIdx.x] = s[0];
}

// --- K2b: exclusive scan of block sums (single block) -----------------------
__global__ __launch_bounds__(256) void k_scanblock(
    const int* __restrict__ blocksums, int* __restrict__ blockoffs)
{
    __shared__ int s[256];
    int tid = threadIdx.x;
    int v = (tid < NBLK_SCAN) ? blocksums[tid] : 0;
    s[tid] = v;
    __syncthreads();
    for (int off = 1; off < 256; off <<= 1) {
        int t = (tid >= off) ? s[tid - off] : 0;
        __syncthreads();
        s[tid] += t;
        __syncthreads();
    }
    if (tid < NBLK_SCAN) blockoffs[tid] = s[tid] - v;   // exclusive
}

// --- K2c: final exclusive scan ----------------------------------------------
__global__ __launch_bounds__(256) void k_scanfinal(
    const int* __restrict__ counts, const int* __restrict__ blockoffs,
    int* __restrict__ offsets)
{
    __shared__ int s[256];
    int tid = threadIdx.x;
    int i = blockIdx.x * 256 + tid;
    int v = (i < N_NODES) ? counts[i] : 0;
    s[tid] = v;
    __syncthreads();
    for (int off = 1; off < 256; off <<= 1) {
        int t = (tid >= off) ? s[tid - off] : 0;
        __syncthreads();
        s[tid] += t;
        __syncthreads();
    }
    if (i < N_NODES) offsets[i] = s[tid] - v + blockoffs[blockIdx.x];
}

// --- K3: edge MLP + placement, 4 edges/thread (4 independent chains) --------
// after this kernel, offsets[n] has become the END offset of node n.
__global__ __launch_bounds__(256) void k_place(
    const int* __restrict__ ei, const float* __restrict__ ea,
    const float* __restrict__ w1, const float* __restrict__ b1,
    const float* __restrict__ w2, const float* __restrict__ b2,
    int* __restrict__ offsets, float4* __restrict__ sorted)
{
    int base = blockIdx.x * 1024 + threadIdx.x;
#pragma unroll
    for (int j = 0; j < 4; ++j) {
        int e = base + j * 256;
        if (e < E_EDGES) {
            int src = ei[e];
            int dst = ei[E_EDGES + e];
            float a = ea[e];
            float wc[C_CH];
#pragma unroll
            for (int c = 0; c < C_CH; ++c) {
                float s = 0.f;
#pragma unroll
                for (int h = 0; h < H_HID; ++h) {
                    float t = fmaf(a, w1[c * H_HID + h], b1[c * H_HID + h]);
                    t = (t >= 0.f) ? t : 0.01f * t;               // leaky_relu
                    s = fmaf(t, w2[c * H_HID + h], s);
                }
                s += b2[c];
                wc[c] = (s > 0.f) ? s : expm1f(s);                // elu
            }
            int pos = atomicAdd(offsets + dst, 1);
            sorted[pos] = make_float4(__int_as_float(src), wc[0], wc[1], wc[2]);
        }
    }
}

// --- K4: gather + residual -> v[N][192] f16 ---------------------------------
// block = 256 thr = 4 waves = 2 nodes; 2 waves split each node's edge range.
__global__ __launch_bounds__(256) void k_gather(
    const float4* __restrict__ sorted, const int* __restrict__ endoff,
    const float* __restrict__ x, const float* __restrict__ eps,
    _Float16* __restrict__ v)
{
    __shared__ float part[2][3][64];     // odd-wave partials, 1.5 KB

    const int tid  = threadIdx.x;
    const int lane = tid & 63;
    const int wid  = tid >> 6;
    const int nl   = wid >> 1;           // node within block (0/1)
    const int half = wid & 1;            // which half of the edge range
    const int n    = blockIdx.x * 2 + nl;   // grid = N/2 exact

    const int start = (n == 0) ? 0 : endoff[n - 1];
    const int end   = endoff[n];
    const int mid   = start + ((end - start + 1) >> 1);
    const int lo    = half ? mid : start;
    const int hi    = half ? end : mid;

    float a0 = 0.f, a1 = 0.f, a2 = 0.f;   // even-edge chain
    float b0 = 0.f, b1 = 0.f, b2 = 0.f;   // odd-edge chain
    int i = lo;
    for (; i + 2 <= hi; i += 2) {
        float4 r0 = sorted[i], r1 = sorted[i + 1];
        float x0 = x[(size_t)__float_as_int(r0.x) * D_FEAT + lane];
        float x1 = x[(size_t)__float_as_int(r1.x) * D_FEAT + lane];
        a0 = fmaf(r0.y, x0, a0); a1 = fmaf(r0.z, x0, a1); a2 = fmaf(r0.w, x0, a2);
        b0 = fmaf(r1.y, x1, b0); b1 = fmaf(r1.z, x1, b1); b2 = fmaf(r1.w, x1, b2);
    }
    if (i < hi) {
        float4 r0 = sorted[i];
        float x0 = x[(size_t)__float_as_int(r0.x) * D_FEAT + lane];
        a0 = fmaf(r0.y, x0, a0); a1 = fmaf(r0.z, x0, a1); a2 = fmaf(r0.w, x0, a2);
    }
    a0 += b0; a1 += b1; a2 += b2;

    if (half) {
        part[nl][0][lane] = a0;
        part[nl][1][lane] = a1;
        part[nl][2][lane] = a2;
    }
    __syncthreads();
    if (!half) {
        a0 += part[nl][0][lane];
        a1 += part[nl][1][lane];
        a2 += part[nl][2][lane];
        float xn = x[(size_t)n * D_FEAT + lane];
        _Float16* vr = v + (size_t)n * CD;
        vr[lane]       = (_Float16)(a0 + (1.f + eps[0]) * xn);
        vr[64 + lane]  = (_Float16)(a1 + (1.f + eps[1]) * xn);
        vr[128 + lane] = (_Float16)(a2 + (1.f + eps[2]) * xn);
    }
}

// --- K5: MLP1(lrelu) + MLP2 via f16 MFMA ------------------------------------
__global__ __launch_bounds__(256) void k_mlp(
    const _Float16* __restrict__ v,
    const float* __restrict__ nw1, const float* __restrict__ nb1,
    const float* __restrict__ nw2, const float* __restrict__ nb2,
    float* __restrict__ out)
{
    __shared__ _Float16 vtile[16][CD + 8];     // stride 400B (16B mult)
    __shared__ _Float16 htile[16][OUT_F + 8];  // stride 272B (16B mult)

    const int tid  = threadIdx.x;
    const int lane = tid & 63;
    const int wid  = tid >> 6;
    const int arow = lane & 15;
    const int kg   = lane >> 4;
    const int o0   = wid * 32;

    half8 w1f[6][2], w2f[4][2];
#pragma unroll
    for (int kk = 0; kk < 6; ++kk)
#pragma unroll
        for (int nt = 0; nt < 2; ++nt) {
            half8 f;
            int colb = o0 + nt * 16 + arow;
            int kb = kk * 32 + kg * 8;
#pragma unroll
            for (int j = 0; j < 8; ++j)
                f[j] = (_Float16)nw1[(size_t)(kb + j) * OUT_F + colb];
            w1f[kk][nt] = f;
        }
#pragma unroll
    for (int kk = 0; kk < 4; ++kk)
#pragma unroll
        for (int nt = 0; nt < 2; ++nt) {
            half8 f;
            int colb = o0 + nt * 16 + arow;
            int kb = kk * 32 + kg * 8;
#pragma unroll
            for (int j = 0; j < 8; ++j)
                f[j] = (_Float16)nw2[(size_t)(kb + j) * OUT_F + colb];
            w2f[kk][nt] = f;
        }

    const float b1a = nb1[o0 + arow],      b1b = nb1[o0 + 16 + arow];
    const float b2a = nb2[o0 + arow],      b2b = nb2[o0 + 16 + arow];

    for (int t = blockIdx.x; t < NTILES; t += gridDim.x) {
        const int nb16 = t * 16;
        __syncthreads();

        for (int i = tid; i < 16 * (CD / 8); i += 256) {    // 384 chunks
            int row = i / (CD / 8), c8 = i % (CD / 8);
            *(half8*)&vtile[row][c8 * 8] =
                *(const half8*)(v + (size_t)(nb16 + row) * CD + c8 * 8);
        }
        __syncthreads();

        f32x4 acc0 = {0.f, 0.f, 0.f, 0.f}, acc1 = {0.f, 0.f, 0.f, 0.f};
#pragma unroll
        for (int kk = 0; kk < 6; ++kk) {
            half8 a = *(const half8*)&vtile[arow][kk * 32 + kg * 8];
            acc0 = __builtin_amdgcn_mfma_f32_16x16x32_f16(a, w1f[kk][0], acc0, 0, 0, 0);
            acc1 = __builtin_amdgcn_mfma_f32_16x16x32_f16(a, w1f[kk][1], acc1, 0, 0, 0);
        }
#pragma unroll
        for (int r = 0; r < 4; ++r) {
            int hr = kg * 4 + r;
            htile[hr][o0 + arow]      = (_Float16)lrelu(acc0[r] + b1a);
            htile[hr][o0 + 16 + arow] = (_Float16)lrelu(acc1[r] + b1b);
        }
        __syncthreads();

        f32x4 c0 = {0.f, 0.f, 0.f, 0.f}, c1 = {0.f, 0.f, 0.f, 0.f};
#pragma unroll
        for (int kk = 0; kk < 4; ++kk) {
            half8 a = *(const half8*)&htile[arow][kk * 32 + kg * 8];
            c0 = __builtin_amdgcn_mfma_f32_16x16x32_f16(a, w2f[kk][0], c0, 0, 0, 0);
            c1 = __builtin_amdgcn_mfma_f32_16x16x32_f16(a, w2f[kk][1], c1, 0, 0, 0);
        }
#pragma unroll
        for (int r = 0; r < 4; ++r) {
            size_t n = (size_t)(nb16 + kg * 4 + r);
            out[n * OUT_F + o0 + arow]      = c0[r] + b2a;
            out[n * OUT_F + o0 + 16 + arow] = c1[r] + b2b;
        }
    }
}

extern "C" void kernel_launch(void* const* d_in, const int* in_sizes, int n_in,
                              void* d_out, int out_size, void* d_ws, size_t ws_size,
                              hipStream_t stream)
{
    const float* x    = (const float*)d_in[0];
    const int*   ei   = (const int*)  d_in[1];
    const float* ea   = (const float*)d_in[2];
    const float* w1   = (const float*)d_in[3];
    const float* b1   = (const float*)d_in[4];
    const float* w2   = (const float*)d_in[5];
    const float* b2   = (const float*)d_in[6];
    const float* eps  = (const float*)d_in[7];
    const float* nw1  = (const float*)d_in[8];
    const float* nb1  = (const float*)d_in[9];
    const float* nw2  = (const float*)d_in[10];
    const float* nb2  = (const float*)d_in[11];
    float* out = (float*)d_out;

    // workspace layout
    char* ws = (char*)d_ws;
    int*       counts    = (int*)    (ws + 0);              // 200 KB
    int*       offsets   = (int*)    (ws + (256 << 10));    // 200 KB
    int*       blocksums = (int*)    (ws + (512 << 10));    // <1 KB
    int*       blockoffs = (int*)    (ws + (516 << 10));    // <1 KB
    float4*    sorted    = (float4*) (ws + (1 << 20));      // 12.8 MB
    _Float16*  v         = (_Float16*)(ws + (16u << 20));   // 19.2 MB

    hipMemsetAsync(counts, 0, N_NODES * sizeof(int), stream);

    k_hist     <<<E_EDGES / 256,            256, 0, stream>>>(ei, counts);
    k_blocksum <<<NBLK_SCAN,                256, 0, stream>>>(counts, blocksums);
    k_scanblock<<<1,                        256, 0, stream>>>(blocksums, blockoffs);
    k_scanfinal<<<NBLK_SCAN,                256, 0, stream>>>(counts, blockoffs, offsets);
    k_place    <<<(E_EDGES + 1023) / 1024,  256, 0, stream>>>(ei, ea, w1, b1, w2, b2, offsets, sorted);
    k_gather   <<<N_NODES / 2,              256, 0, stream>>>(sorted, offsets, x, eps, v);
    k_mlp      <<<768,                      256, 0, stream>>>(v, nw1, nb1, nw2, nb2, out);
}

// Round 7
// 169.415 us; speedup vs baseline: 6.9283x; 1.0729x over previous
//
#include <hip/hip_runtime.h>
#include <math.h>

#define N_NODES 50000
#define E_EDGES 800000
#define D_FEAT  64
#define C_CH    3
#define H_HID   8
#define OUT_F   128
#define CD      192              // C*D
#define NTILES  (N_NODES / 16)   // 3125 exact
#define NBLK_SCAN ((N_NODES + 255) / 256)   // 196

typedef _Float16 half8 __attribute__((ext_vector_type(8)));
typedef float f32x4 __attribute__((ext_vector_type(4)));

__device__ __forceinline__ float lrelu(float v) { return v >= 0.f ? v : 0.01f * v; }

__device__ __forceinline__ unsigned short f2h_bits(float f) {
    _Float16 h = (_Float16)f;
    unsigned short b;
    __builtin_memcpy(&b, &h, 2);
    return b;
}
__device__ __forceinline__ float h2f_bits(unsigned b) {
    unsigned short s = (unsigned short)b;
    _Float16 h;
    __builtin_memcpy(&h, &s, 2);
    return (float)h;
}

// --- K1: edge MLP -> packed 8B record (coalesced) + dst histogram -----------
// record uint2: x = src | (w0<<16), y = w1 | (w2<<16)   (w* = f16 bits)
__global__ __launch_bounds__(256) void k_prep(
    const int* __restrict__ ei, const float* __restrict__ ea,
    const float* __restrict__ w1, const float* __restrict__ b1,
    const float* __restrict__ w2, const float* __restrict__ b2,
    uint2* __restrict__ wbuf, int* __restrict__ counts)
{
    int e = blockIdx.x * 256 + threadIdx.x;      // grid covers E exactly
    int src = ei[e];
    int dst = ei[E_EDGES + e];
    float a = ea[e];
    float wc[C_CH];
#pragma unroll
    for (int c = 0; c < C_CH; ++c) {
        float s = 0.f;
#pragma unroll
        for (int h = 0; h < H_HID; ++h) {
            float t = fmaf(a, w1[c * H_HID + h], b1[c * H_HID + h]);
            t = (t >= 0.f) ? t : 0.01f * t;               // leaky_relu
            s = fmaf(t, w2[c * H_HID + h], s);
        }
        s += b2[c];
        wc[c] = (s > 0.f) ? s : expm1f(s);                // elu
    }
    uint2 r;
    r.x = (unsigned)src | ((unsigned)f2h_bits(wc[0]) << 16);
    r.y = (unsigned)f2h_bits(wc[1]) | ((unsigned)f2h_bits(wc[2]) << 16);
    wbuf[e] = r;
    atomicAdd(counts + dst, 1);      // return value unused -> no latency chain
}

// --- K2a: per-block sums of counts ------------------------------------------
__global__ __launch_bounds__(256) void k_blocksum(
    const int* __restrict__ counts, int* __restrict__ blocksums)
{
    __shared__ int s[256];
    int i = blockIdx.x * 256 + threadIdx.x;
    s[threadIdx.x] = (i < N_NODES) ? counts[i] : 0;
    __syncthreads();
    for (int off = 128; off >= 1; off >>= 1) {
        if (threadIdx.x < off) s[threadIdx.x] += s[threadIdx.x + off];
        __syncthreads();
    }
    if (threadIdx.x == 0) blocksums[blockIdx.x] = s[0];
}

// --- K2b: exclusive scan of block sums (single block) -----------------------
__global__ __launch_bounds__(256) void k_scanblock(
    const int* __restrict__ blocksums, int* __restrict__ blockoffs)
{
    __shared__ int s[256];
    int tid = threadIdx.x;
    int v = (tid < NBLK_SCAN) ? blocksums[tid] : 0;
    s[tid] = v;
    __syncthreads();
    for (int off = 1; off < 256; off <<= 1) {
        int t = (tid >= off) ? s[tid - off] : 0;
        __syncthreads();
        s[tid] += t;
        __syncthreads();
    }
    if (tid < NBLK_SCAN) blockoffs[tid] = s[tid] - v;   // exclusive
}

// --- K2c: final exclusive scan ----------------------------------------------
__global__ __launch_bounds__(256) void k_scanfinal(
    const int* __restrict__ counts, const int* __restrict__ blockoffs,
    int* __restrict__ offsets)
{
    __shared__ int s[256];
    int tid = threadIdx.x;
    int i = blockIdx.x * 256 + tid;
    int v = (i < N_NODES) ? counts[i] : 0;
    s[tid] = v;
    __syncthreads();
    for (int off = 1; off < 256; off <<= 1) {
        int t = (tid >= off) ? s[tid - off] : 0;
        __syncthreads();
        s[tid] += t;
        __syncthreads();
    }
    if (i < N_NODES) offsets[i] = s[tid] - v + blockoffs[blockIdx.x];
}

// --- K3: scatter edge index into dst-sorted perm (4B, L2-resident) ----------
// after this kernel, offsets[n] has become the END offset of node n.
__global__ __launch_bounds__(256) void k_place(
    const int* __restrict__ ei, int* __restrict__ offsets,
    int* __restrict__ perm)
{
    int e = blockIdx.x * 256 + threadIdx.x;
    int dst = ei[E_EDGES + e];
    int pos = atomicAdd(offsets + dst, 1);
    perm[pos] = e;
}

// --- K4: gather + residual -> v[N][192] f16 ---------------------------------
// one wave per node; 64 lanes batch-fetch up to 64 edge records in parallel,
// then shfl-broadcast each record while lanes gather x rows (lane = feature).
__global__ __launch_bounds__(256) void k_gather(
    const int* __restrict__ perm, const int* __restrict__ endoff,
    const uint2* __restrict__ wbuf, const float* __restrict__ x,
    const float* __restrict__ eps, _Float16* __restrict__ v)
{
    const int n    = blockIdx.x * 4 + (threadIdx.x >> 6);   // grid = N/4 exact
    const int lane = threadIdx.x & 63;

    const int start = (n == 0) ? 0 : endoff[n - 1];
    const int end   = endoff[n];

    float a0 = 0.f, a1 = 0.f, a2 = 0.f;   // even chain
    float b0 = 0.f, b1 = 0.f, b2 = 0.f;   // odd chain

    for (int base = start; base < end; base += 64) {
        const int m = min(64, end - base);
        uint2 rec = make_uint2(0u, 0u);
        if (lane < m) {
            int p = perm[base + lane];     // coalesced 4B
            rec = wbuf[p];                 // random 8B, L2/L3-resident
        }
        int j = 0;
        for (; j + 2 <= m; j += 2) {
            unsigned rx0 = (unsigned)__shfl((int)rec.x, j);
            unsigned ry0 = (unsigned)__shfl((int)rec.y, j);
            unsigned rx1 = (unsigned)__shfl((int)rec.x, j + 1);
            unsigned ry1 = (unsigned)__shfl((int)rec.y, j + 1);
            float xa = x[(size_t)(rx0 & 0xFFFFu) * D_FEAT + lane];
            float xb = x[(size_t)(rx1 & 0xFFFFu) * D_FEAT + lane];
            a0 = fmaf(h2f_bits(rx0 >> 16),      xa, a0);
            a1 = fmaf(h2f_bits(ry0 & 0xFFFFu),  xa, a1);
            a2 = fmaf(h2f_bits(ry0 >> 16),      xa, a2);
            b0 = fmaf(h2f_bits(rx1 >> 16),      xb, b0);
            b1 = fmaf(h2f_bits(ry1 & 0xFFFFu),  xb, b1);
            b2 = fmaf(h2f_bits(ry1 >> 16),      xb, b2);
        }
        if (j < m) {
            unsigned rx0 = (unsigned)__shfl((int)rec.x, j);
            unsigned ry0 = (unsigned)__shfl((int)rec.y, j);
            float xa = x[(size_t)(rx0 & 0xFFFFu) * D_FEAT + lane];
            a0 = fmaf(h2f_bits(rx0 >> 16),      xa, a0);
            a1 = fmaf(h2f_bits(ry0 & 0xFFFFu),  xa, a1);
            a2 = fmaf(h2f_bits(ry0 >> 16),      xa, a2);
        }
    }
    a0 += b0; a1 += b1; a2 += b2;

    float xn = x[(size_t)n * D_FEAT + lane];
    _Float16* vr = v + (size_t)n * CD;
    vr[lane]       = (_Float16)(a0 + (1.f + eps[0]) * xn);
    vr[64 + lane]  = (_Float16)(a1 + (1.f + eps[1]) * xn);
    vr[128 + lane] = (_Float16)(a2 + (1.f + eps[2]) * xn);
}

// --- K5: MLP1(lrelu) + MLP2 via f16 MFMA ------------------------------------
__global__ __launch_bounds__(256) void k_mlp(
    const _Float16* __restrict__ v,
    const float* __restrict__ nw1, const float* __restrict__ nb1,
    const float* __restrict__ nw2, const float* __restrict__ nb2,
    float* __restrict__ out)
{
    __shared__ _Float16 vtile[16][CD + 8];     // stride 400B (16B mult)
    __shared__ _Float16 htile[16][OUT_F + 8];  // stride 272B (16B mult)

    const int tid  = threadIdx.x;
    const int lane = tid & 63;
    const int wid  = tid >> 6;
    const int arow = lane & 15;
    const int kg   = lane >> 4;
    const int o0   = wid * 32;

    half8 w1f[6][2], w2f[4][2];
#pragma unroll
    for (int kk = 0; kk < 6; ++kk)
#pragma unroll
        for (int nt = 0; nt < 2; ++nt) {
            half8 f;
            int colb = o0 + nt * 16 + arow;
            int kb = kk * 32 + kg * 8;
#pragma unroll
            for (int j = 0; j < 8; ++j)
                f[j] = (_Float16)nw1[(size_t)(kb + j) * OUT_F + colb];
            w1f[kk][nt] = f;
        }
#pragma unroll
    for (int kk = 0; kk < 4; ++kk)
#pragma unroll
        for (int nt = 0; nt < 2; ++nt) {
            half8 f;
            int colb = o0 + nt * 16 + arow;
            int kb = kk * 32 + kg * 8;
#pragma unroll
            for (int j = 0; j < 8; ++j)
                f[j] = (_Float16)nw2[(size_t)(kb + j) * OUT_F + colb];
            w2f[kk][nt] = f;
        }

    const float b1a = nb1[o0 + arow],      b1b = nb1[o0 + 16 + arow];
    const float b2a = nb2[o0 + arow],      b2b = nb2[o0 + 16 + arow];

    for (int t = blockIdx.x; t < NTILES; t += gridDim.x) {
        const int nb16 = t * 16;
        __syncthreads();

        for (int i = tid; i < 16 * (CD / 8); i += 256) {    // 384 chunks
            int row = i / (CD / 8), c8 = i % (CD / 8);
            *(half8*)&vtile[row][c8 * 8] =
                *(const half8*)(v + (size_t)(nb16 + row) * CD + c8 * 8);
        }
        __syncthreads();

        f32x4 acc0 = {0.f, 0.f, 0.f, 0.f}, acc1 = {0.f, 0.f, 0.f, 0.f};
#pragma unroll
        for (int kk = 0; kk < 6; ++kk) {
            half8 a = *(const half8*)&vtile[arow][kk * 32 + kg * 8];
            acc0 = __builtin_amdgcn_mfma_f32_16x16x32_f16(a, w1f[kk][0], acc0, 0, 0, 0);
            acc1 = __builtin_amdgcn_mfma_f32_16x16x32_f16(a, w1f[kk][1], acc1, 0, 0, 0);
        }
#pragma unroll
        for (int r = 0; r < 4; ++r) {
            int hr = kg * 4 + r;
            htile[hr][o0 + arow]      = (_Float16)lrelu(acc0[r] + b1a);
            htile[hr][o0 + 16 + arow] = (_Float16)lrelu(acc1[r] + b1b);
        }
        __syncthreads();

        f32x4 c0 = {0.f, 0.f, 0.f, 0.f}, c1 = {0.f, 0.f, 0.f, 0.f};
#pragma unroll
        for (int kk = 0; kk < 4; ++kk) {
            half8 a = *(const half8*)&htile[arow][kk * 32 + kg * 8];
            c0 = __builtin_amdgcn_mfma_f32_16x16x32_f16(a, w2f[kk][0], c0, 0, 0, 0);
            c1 = __builtin_amdgcn_mfma_f32_16x16x32_f16(a, w2f[kk][1], c1, 0, 0, 0);
        }
#pragma unroll
        for (int r = 0; r < 4; ++r) {
            size_t n = (size_t)(nb16 + kg * 4 + r);
            out[n * OUT_F + o0 + arow]      = c0[r] + b2a;
            out[n * OUT_F + o0 + 16 + arow] = c1[r] + b2b;
        }
    }
}

extern "C" void kernel_launch(void* const* d_in, const int* in_sizes, int n_in,
                              void* d_out, int out_size, void* d_ws, size_t ws_size,
                              hipStream_t stream)
{
    const float* x    = (const float*)d_in[0];
    const int*   ei   = (const int*)  d_in[1];
    const float* ea   = (const float*)d_in[2];
    const float* w1   = (const float*)d_in[3];
    const float* b1   = (const float*)d_in[4];
    const float* w2   = (const float*)d_in[5];
    const float* b2   = (const float*)d_in[6];
    const float* eps  = (const float*)d_in[7];
    const float* nw1  = (const float*)d_in[8];
    const float* nb1  = (const float*)d_in[9];
    const float* nw2  = (const float*)d_in[10];
    const float* nb2  = (const float*)d_in[11];
    float* out = (float*)d_out;

    // workspace layout
    char* ws = (char*)d_ws;
    int*       counts    = (int*)    (ws + 0);              // 200 KB
    int*       offsets   = (int*)    (ws + (256 << 10));    // 200 KB
    int*       blocksums = (int*)    (ws + (512 << 10));    // <1 KB
    int*       blockoffs = (int*)    (ws + (516 << 10));    // <1 KB
    int*       perm      = (int*)    (ws + (1 << 20));      // 3.2 MB
    uint2*     wbuf      = (uint2*)  (ws + (8u << 20));     // 6.4 MB
    _Float16*  v         = (_Float16*)(ws + (16u << 20));   // 19.2 MB

    hipMemsetAsync(counts, 0, N_NODES * sizeof(int), stream);

    k_prep     <<<E_EDGES / 256, 256, 0, stream>>>(ei, ea, w1, b1, w2, b2, wbuf, counts);
    k_blocksum <<<NBLK_SCAN,     256, 0, stream>>>(counts, blocksums);
    k_scanblock<<<1,             256, 0, stream>>>(blocksums, blockoffs);
    k_scanfinal<<<NBLK_SCAN,     256, 0, stream>>>(counts, blockoffs, offsets);
    k_place    <<<E_EDGES / 256, 256, 0, stream>>>(ei, offsets, perm);
    k_gather   <<<N_NODES / 4,   256, 0, stream>>>(perm, offsets, wbuf, x, eps, v);
    k_mlp      <<<768,           256, 0, stream>>>(v, nw1, nb1, nw2, nb2, out);
}

// Round 8
// 154.274 us; speedup vs baseline: 7.6082x; 1.0981x over previous
//
#include <hip/hip_runtime.h>
#include <math.h>

#define N_NODES 50000
#define E_EDGES 800000
#define D_FEAT  64
#define C_CH    3
#define H_HID   8
#define OUT_F   128
#define CD      192              // C*D
#define NTILES  (N_NODES / 16)   // 3125 exact
#define NBLK_SCAN ((N_NODES + 255) / 256)   // 196
#define PLACE_CHUNK  1024
#define PLACE_SLICES ((E_EDGES + PLACE_CHUNK - 1) / PLACE_CHUNK)  // 782
#define NPART8 (N_NODES / 8)     // 6250 exact

typedef _Float16 half8 __attribute__((ext_vector_type(8)));
typedef float f32x4 __attribute__((ext_vector_type(4)));

__device__ __forceinline__ float lrelu(float v) { return v >= 0.f ? v : 0.01f * v; }

__device__ __forceinline__ unsigned short f2h_bits(float f) {
    _Float16 h = (_Float16)f;
    unsigned short b;
    __builtin_memcpy(&b, &h, 2);
    return b;
}
__device__ __forceinline__ float h2f_bits(unsigned b) {
    unsigned short s = (unsigned short)b;
    _Float16 h;
    __builtin_memcpy(&h, &s, 2);
    return (float)h;
}

// --- K1: edge MLP -> packed 8B record (coalesced) + dst histogram -----------
// record uint2: x = src | (w0<<16), y = w1 | (w2<<16)   (w* = f16 bits)
__global__ __launch_bounds__(256) void k_prep(
    const int* __restrict__ ei, const float* __restrict__ ea,
    const float* __restrict__ w1, const float* __restrict__ b1,
    const float* __restrict__ w2, const float* __restrict__ b2,
    uint2* __restrict__ wbuf, int* __restrict__ counts)
{
    int e = blockIdx.x * 256 + threadIdx.x;      // grid covers E exactly
    int src = ei[e];
    int dst = ei[E_EDGES + e];
    float a = ea[e];
    float wc[C_CH];
#pragma unroll
    for (int c = 0; c < C_CH; ++c) {
        float s = 0.f;
#pragma unroll
        for (int h = 0; h < H_HID; ++h) {
            float t = fmaf(a, w1[c * H_HID + h], b1[c * H_HID + h]);
            t = (t >= 0.f) ? t : 0.01f * t;               // leaky_relu
            s = fmaf(t, w2[c * H_HID + h], s);
        }
        s += b2[c];
        wc[c] = (s > 0.f) ? s : expm1f(s);                // elu
    }
    uint2 r;
    r.x = (unsigned)src | ((unsigned)f2h_bits(wc[0]) << 16);
    r.y = (unsigned)f2h_bits(wc[1]) | ((unsigned)f2h_bits(wc[2]) << 16);
    wbuf[e] = r;
    atomicAdd(counts + dst, 1);      // return value unused -> no latency chain
}

// --- K2a: per-block sums of counts ------------------------------------------
__global__ __launch_bounds__(256) void k_blocksum(
    const int* __restrict__ counts, int* __restrict__ blocksums)
{
    __shared__ int s[256];
    int i = blockIdx.x * 256 + threadIdx.x;
    s[threadIdx.x] = (i < N_NODES) ? counts[i] : 0;
    __syncthreads();
    for (int off = 128; off >= 1; off >>= 1) {
        if (threadIdx.x < off) s[threadIdx.x] += s[threadIdx.x + off];
        __syncthreads();
    }
    if (threadIdx.x == 0) blocksums[blockIdx.x] = s[0];
}

// --- K2b: exclusive scan of block sums (single block) -----------------------
__global__ __launch_bounds__(256) void k_scanblock(
    const int* __restrict__ blocksums, int* __restrict__ blockoffs)
{
    __shared__ int s[256];
    int tid = threadIdx.x;
    int v = (tid < NBLK_SCAN) ? blocksums[tid] : 0;
    s[tid] = v;
    __syncthreads();
    for (int off = 1; off < 256; off <<= 1) {
        int t = (tid >= off) ? s[tid - off] : 0;
        __syncthreads();
        s[tid] += t;
        __syncthreads();
    }
    if (tid < NBLK_SCAN) blockoffs[tid] = s[tid] - v;   // exclusive
}

// --- K2c: final exclusive scan ----------------------------------------------
__global__ __launch_bounds__(256) void k_scanfinal(
    const int* __restrict__ counts, const int* __restrict__ blockoffs,
    int* __restrict__ offsets)
{
    __shared__ int s[256];
    int tid = threadIdx.x;
    int i = blockIdx.x * 256 + tid;
    int v = (i < N_NODES) ? counts[i] : 0;
    s[tid] = v;
    __syncthreads();
    for (int off = 1; off < 256; off <<= 1) {
        int t = (tid >= off) ? s[tid - off] : 0;
        __syncthreads();
        s[tid] += t;
        __syncthreads();
    }
    if (i < N_NODES) offsets[i] = s[tid] - v + blockoffs[blockIdx.x];
}

// --- K3: XCD-partitioned scatter of edge index into dst-sorted perm ---------
// group g = blockIdx&7 (round-robin -> one XCD) owns dst range
// [g*6250, (g+1)*6250): its offsets cursors and perm region stay in ONE
// XCD's L2, eliminating cross-XCD line ping-pong. Each group scans all
// edges (dst array is L2-resident). offsets become per-node END offsets.
__global__ __launch_bounds__(256) void k_place(
    const int* __restrict__ ei, int* __restrict__ offsets,
    int* __restrict__ perm)
{
    const int g     = blockIdx.x & 7;
    const int slice = blockIdx.x >> 3;
    const int lo    = g * NPART8;
    const int hi    = lo + NPART8;
    const int e0    = slice * PLACE_CHUNK + threadIdx.x * 4;
    const int* dstp = ei + E_EDGES;

    if (e0 + 3 < E_EDGES) {
        int4 d = *(const int4*)(dstp + e0);
        if (d.x >= lo && d.x < hi) perm[atomicAdd(offsets + d.x, 1)] = e0;
        if (d.y >= lo && d.y < hi) perm[atomicAdd(offsets + d.y, 1)] = e0 + 1;
        if (d.z >= lo && d.z < hi) perm[atomicAdd(offsets + d.z, 1)] = e0 + 2;
        if (d.w >= lo && d.w < hi) perm[atomicAdd(offsets + d.w, 1)] = e0 + 3;
    } else {
#pragma unroll
        for (int j = 0; j < 4; ++j) {
            int e = e0 + j;
            if (e < E_EDGES) {
                int dd = dstp[e];
                if (dd >= lo && dd < hi) perm[atomicAdd(offsets + dd, 1)] = e;
            }
        }
    }
}

// --- K4: gather + residual -> v[N][192] f16 ---------------------------------
// one wave per node; 64 lanes batch-fetch up to 64 edge records in parallel,
// then shfl-broadcast each record while lanes gather x rows (lane = feature).
__global__ __launch_bounds__(256) void k_gather(
    const int* __restrict__ perm, const int* __restrict__ endoff,
    const uint2* __restrict__ wbuf, const float* __restrict__ x,
    const float* __restrict__ eps, _Float16* __restrict__ v)
{
    const int n    = blockIdx.x * 4 + (threadIdx.x >> 6);   // grid = N/4 exact
    const int lane = threadIdx.x & 63;

    const int start = (n == 0) ? 0 : endoff[n - 1];
    const int end   = endoff[n];

    float a0 = 0.f, a1 = 0.f, a2 = 0.f;   // even chain
    float b0 = 0.f, b1 = 0.f, b2 = 0.f;   // odd chain

    for (int base = start; base < end; base += 64) {
        const int m = min(64, end - base);
        uint2 rec = make_uint2(0u, 0u);
        if (lane < m) {
            int p = perm[base + lane];     // coalesced 4B
            rec = wbuf[p];                 // random 8B, L2/L3-resident
        }
        int j = 0;
        for (; j + 2 <= m; j += 2) {
            unsigned rx0 = (unsigned)__shfl((int)rec.x, j);
            unsigned ry0 = (unsigned)__shfl((int)rec.y, j);
            unsigned rx1 = (unsigned)__shfl((int)rec.x, j + 1);
            unsigned ry1 = (unsigned)__shfl((int)rec.y, j + 1);
            float xa = x[(size_t)(rx0 & 0xFFFFu) * D_FEAT + lane];
            float xb = x[(size_t)(rx1 & 0xFFFFu) * D_FEAT + lane];
            a0 = fmaf(h2f_bits(rx0 >> 16),      xa, a0);
            a1 = fmaf(h2f_bits(ry0 & 0xFFFFu),  xa, a1);
            a2 = fmaf(h2f_bits(ry0 >> 16),      xa, a2);
            b0 = fmaf(h2f_bits(rx1 >> 16),      xb, b0);
            b1 = fmaf(h2f_bits(ry1 & 0xFFFFu),  xb, b1);
            b2 = fmaf(h2f_bits(ry1 >> 16),      xb, b2);
        }
        if (j < m) {
            unsigned rx0 = (unsigned)__shfl((int)rec.x, j);
            unsigned ry0 = (unsigned)__shfl((int)rec.y, j);
            float xa = x[(size_t)(rx0 & 0xFFFFu) * D_FEAT + lane];
            a0 = fmaf(h2f_bits(rx0 >> 16),      xa, a0);
            a1 = fmaf(h2f_bits(ry0 & 0xFFFFu),  xa, a1);
            a2 = fmaf(h2f_bits(ry0 >> 16),      xa, a2);
        }
    }
    a0 += b0; a1 += b1; a2 += b2;

    float xn = x[(size_t)n * D_FEAT + lane];
    _Float16* vr = v + (size_t)n * CD;
    vr[lane]       = (_Float16)(a0 + (1.f + eps[0]) * xn);
    vr[64 + lane]  = (_Float16)(a1 + (1.f + eps[1]) * xn);
    vr[128 + lane] = (_Float16)(a2 + (1.f + eps[2]) * xn);
}

// --- K5: MLP1(lrelu) + MLP2 via f16 MFMA ------------------------------------
__global__ __launch_bounds__(256) void k_mlp(
    const _Float16* __restrict__ v,
    const float* __restrict__ nw1, const float* __restrict__ nb1,
    const float* __restrict__ nw2, const float* __restrict__ nb2,
    float* __restrict__ out)
{
    __shared__ _Float16 vtile[16][CD + 8];     // stride 400B (16B mult)
    __shared__ _Float16 htile[16][OUT_F + 8];  // stride 272B (16B mult)

    const int tid  = threadIdx.x;
    const int lane = tid & 63;
    const int wid  = tid >> 6;
    const int arow = lane & 15;
    const int kg   = lane >> 4;
    const int o0   = wid * 32;

    half8 w1f[6][2], w2f[4][2];
#pragma unroll
    for (int kk = 0; kk < 6; ++kk)
#pragma unroll
        for (int nt = 0; nt < 2; ++nt) {
            half8 f;
            int colb = o0 + nt * 16 + arow;
            int kb = kk * 32 + kg * 8;
#pragma unroll
            for (int j = 0; j < 8; ++j)
                f[j] = (_Float16)nw1[(size_t)(kb + j) * OUT_F + colb];
            w1f[kk][nt] = f;
        }
#pragma unroll
    for (int kk = 0; kk < 4; ++kk)
#pragma unroll
        for (int nt = 0; nt < 2; ++nt) {
            half8 f;
            int colb = o0 + nt * 16 + arow;
            int kb = kk * 32 + kg * 8;
#pragma unroll
            for (int j = 0; j < 8; ++j)
                f[j] = (_Float16)nw2[(size_t)(kb + j) * OUT_F + colb];
            w2f[kk][nt] = f;
        }

    const float b1a = nb1[o0 + arow],      b1b = nb1[o0 + 16 + arow];
    const float b2a = nb2[o0 + arow],      b2b = nb2[o0 + 16 + arow];

    for (int t = blockIdx.x; t < NTILES; t += gridDim.x) {
        const int nb16 = t * 16;
        __syncthreads();

        for (int i = tid; i < 16 * (CD / 8); i += 256) {    // 384 chunks
            int row = i / (CD / 8), c8 = i % (CD / 8);
            *(half8*)&vtile[row][c8 * 8] =
                *(const half8*)(v + (size_t)(nb16 + row) * CD + c8 * 8);
        }
        __syncthreads();

        f32x4 acc0 = {0.f, 0.f, 0.f, 0.f}, acc1 = {0.f, 0.f, 0.f, 0.f};
#pragma unroll
        for (int kk = 0; kk < 6; ++kk) {
            half8 a = *(const half8*)&vtile[arow][kk * 32 + kg * 8];
            acc0 = __builtin_amdgcn_mfma_f32_16x16x32_f16(a, w1f[kk][0], acc0, 0, 0, 0);
            acc1 = __builtin_amdgcn_mfma_f32_16x16x32_f16(a, w1f[kk][1], acc1, 0, 0, 0);
        }
#pragma unroll
        for (int r = 0; r < 4; ++r) {
            int hr = kg * 4 + r;
            htile[hr][o0 + arow]      = (_Float16)lrelu(acc0[r] + b1a);
            htile[hr][o0 + 16 + arow] = (_Float16)lrelu(acc1[r] + b1b);
        }
        __syncthreads();

        f32x4 c0 = {0.f, 0.f, 0.f, 0.f}, c1 = {0.f, 0.f, 0.f, 0.f};
#pragma unroll
        for (int kk = 0; kk < 4; ++kk) {
            half8 a = *(const half8*)&htile[arow][kk * 32 + kg * 8];
            c0 = __builtin_amdgcn_mfma_f32_16x16x32_f16(a, w2f[kk][0], c0, 0, 0, 0);
            c1 = __builtin_amdgcn_mfma_f32_16x16x32_f16(a, w2f[kk][1], c1, 0, 0, 0);
        }
#pragma unroll
        for (int r = 0; r < 4; ++r) {
            size_t n = (size_t)(nb16 + kg * 4 + r);
            out[n * OUT_F + o0 + arow]      = c0[r] + b2a;
            out[n * OUT_F + o0 + 16 + arow] = c1[r] + b2b;
        }
    }
}

extern "C" void kernel_launch(void* const* d_in, const int* in_sizes, int n_in,
                              void* d_out, int out_size, void* d_ws, size_t ws_size,
                              hipStream_t stream)
{
    const float* x    = (const float*)d_in[0];
    const int*   ei   = (const int*)  d_in[1];
    const float* ea   = (const float*)d_in[2];
    const float* w1   = (const float*)d_in[3];
    const float* b1   = (const float*)d_in[4];
    const float* w2   = (const float*)d_in[5];
    const float* b2   = (const float*)d_in[6];
    const float* eps  = (const float*)d_in[7];
    const float* nw1  = (const float*)d_in[8];
    const float* nb1  = (const float*)d_in[9];
    const float* nw2  = (const float*)d_in[10];
    const float* nb2  = (const float*)d_in[11];
    float* out = (float*)d_out;

    // workspace layout
    char* ws = (char*)d_ws;
    int*       counts    = (int*)    (ws + 0);              // 200 KB
    int*       offsets   = (int*)    (ws + (256 << 10));    // 200 KB
    int*       blocksums = (int*)    (ws + (512 << 10));    // <1 KB
    int*       blockoffs = (int*)    (ws + (516 << 10));    // <1 KB
    int*       perm      = (int*)    (ws + (1 << 20));      // 3.2 MB
    uint2*     wbuf      = (uint2*)  (ws + (8u << 20));     // 6.4 MB
    _Float16*  v         = (_Float16*)(ws + (16u << 20));   // 19.2 MB

    hipMemsetAsync(counts, 0, N_NODES * sizeof(int), stream);

    k_prep     <<<E_EDGES / 256,    256, 0, stream>>>(ei, ea, w1, b1, w2, b2, wbuf, counts);
    k_blocksum <<<NBLK_SCAN,        256, 0, stream>>>(counts, blocksums);
    k_scanblock<<<1,                256, 0, stream>>>(blocksums, blockoffs);
    k_scanfinal<<<NBLK_SCAN,        256, 0, stream>>>(counts, blockoffs, offsets);
    k_place    <<<PLACE_SLICES * 8, 256, 0, stream>>>(ei, offsets, perm);
    k_gather   <<<N_NODES / 4,      256, 0, stream>>>(perm, offsets, wbuf, x, eps, v);
    k_mlp      <<<768,              256, 0, stream>>>(v, nw1, nb1, nw2, nb2, out);
}

// Round 9
// 147.307 us; speedup vs baseline: 7.9681x; 1.0473x over previous
//
#include <hip/hip_runtime.h>
#include <math.h>

#define N_NODES 50000
#define E_EDGES 800000
#define D_FEAT  64
#define C_CH    3
#define H_HID   8
#define OUT_F   128
#define CD      192              // C*D
#define NTILES  (N_NODES / 16)   // 3125 exact
#define NBLK_SCAN ((N_NODES + 255) / 256)   // 196
#define PLACE_CHUNK  1024
#define PLACE_SLICES ((E_EDGES + PLACE_CHUNK - 1) / PLACE_CHUNK)  // 782
#define NPART8 (N_NODES / 8)     // 6250 exact

typedef _Float16 half8 __attribute__((ext_vector_type(8)));
typedef _Float16 half4 __attribute__((ext_vector_type(4)));
typedef float f32x4 __attribute__((ext_vector_type(4)));

__device__ __forceinline__ float lrelu(float v) { return v >= 0.f ? v : 0.01f * v; }

__device__ __forceinline__ unsigned short f2h_bits(float f) {
    _Float16 h = (_Float16)f;
    unsigned short b;
    __builtin_memcpy(&b, &h, 2);
    return b;
}
__device__ __forceinline__ float h2f_bits(unsigned b) {
    unsigned short s = (unsigned short)b;
    _Float16 h;
    __builtin_memcpy(&h, &s, 2);
    return (float)h;
}

// --- K0: x f32 -> f16 (coalesced, 4 elems/thread) ---------------------------
__global__ __launch_bounds__(256) void k_xcvt(
    const float* __restrict__ x, _Float16* __restrict__ xh)
{
    int i = blockIdx.x * 256 + threadIdx.x;     // grid = N*D/4/256 exact
    float4 f = ((const float4*)x)[i];
    half4 h;
    h[0] = (_Float16)f.x; h[1] = (_Float16)f.y;
    h[2] = (_Float16)f.z; h[3] = (_Float16)f.w;
    *(half4*)(xh + (size_t)i * 4) = h;
}

// --- K1: edge MLP -> packed 8B record (coalesced) + dst histogram -----------
// record uint2: x = src | (w0<<16), y = w1 | (w2<<16)   (w* = f16 bits)
__global__ __launch_bounds__(256) void k_prep(
    const int* __restrict__ ei, const float* __restrict__ ea,
    const float* __restrict__ w1, const float* __restrict__ b1,
    const float* __restrict__ w2, const float* __restrict__ b2,
    uint2* __restrict__ wbuf, int* __restrict__ counts)
{
    int e = blockIdx.x * 256 + threadIdx.x;      // grid covers E exactly
    int src = ei[e];
    int dst = ei[E_EDGES + e];
    float a = ea[e];
    float wc[C_CH];
#pragma unroll
    for (int c = 0; c < C_CH; ++c) {
        float s = 0.f;
#pragma unroll
        for (int h = 0; h < H_HID; ++h) {
            float t = fmaf(a, w1[c * H_HID + h], b1[c * H_HID + h]);
            t = (t >= 0.f) ? t : 0.01f * t;               // leaky_relu
            s = fmaf(t, w2[c * H_HID + h], s);
        }
        s += b2[c];
        wc[c] = (s > 0.f) ? s : expm1f(s);                // elu
    }
    uint2 r;
    r.x = (unsigned)src | ((unsigned)f2h_bits(wc[0]) << 16);
    r.y = (unsigned)f2h_bits(wc[1]) | ((unsigned)f2h_bits(wc[2]) << 16);
    wbuf[e] = r;
    atomicAdd(counts + dst, 1);      // return value unused -> no latency chain
}

// --- K2a: per-block sums of counts ------------------------------------------
__global__ __launch_bounds__(256) void k_blocksum(
    const int* __restrict__ counts, int* __restrict__ blocksums)
{
    __shared__ int s[256];
    int i = blockIdx.x * 256 + threadIdx.x;
    s[threadIdx.x] = (i < N_NODES) ? counts[i] : 0;
    __syncthreads();
    for (int off = 128; off >= 1; off >>= 1) {
        if (threadIdx.x < off) s[threadIdx.x] += s[threadIdx.x + off];
        __syncthreads();
    }
    if (threadIdx.x == 0) blocksums[blockIdx.x] = s[0];
}

// --- K2b: exclusive scan of block sums (single block) -----------------------
__global__ __launch_bounds__(256) void k_scanblock(
    const int* __restrict__ blocksums, int* __restrict__ blockoffs)
{
    __shared__ int s[256];
    int tid = threadIdx.x;
    int v = (tid < NBLK_SCAN) ? blocksums[tid] : 0;
    s[tid] = v;
    __syncthreads();
    for (int off = 1; off < 256; off <<= 1) {
        int t = (tid >= off) ? s[tid - off] : 0;
        __syncthreads();
        s[tid] += t;
        __syncthreads();
    }
    if (tid < NBLK_SCAN) blockoffs[tid] = s[tid] - v;   // exclusive
}

// --- K2c: final exclusive scan ----------------------------------------------
__global__ __launch_bounds__(256) void k_scanfinal(
    const int* __restrict__ counts, const int* __restrict__ blockoffs,
    int* __restrict__ offsets)
{
    __shared__ int s[256];
    int tid = threadIdx.x;
    int i = blockIdx.x * 256 + tid;
    int v = (i < N_NODES) ? counts[i] : 0;
    s[tid] = v;
    __syncthreads();
    for (int off = 1; off < 256; off <<= 1) {
        int t = (tid >= off) ? s[tid - off] : 0;
        __syncthreads();
        s[tid] += t;
        __syncthreads();
    }
    if (i < N_NODES) offsets[i] = s[tid] - v + blockoffs[blockIdx.x];
}

// --- K3: XCD-partitioned scatter of edge index into dst-sorted perm ---------
__global__ __launch_bounds__(256) void k_place(
    const int* __restrict__ ei, int* __restrict__ offsets,
    int* __restrict__ perm)
{
    const int g     = blockIdx.x & 7;
    const int slice = blockIdx.x >> 3;
    const int lo    = g * NPART8;
    const int hi    = lo + NPART8;
    const int e0    = slice * PLACE_CHUNK + threadIdx.x * 4;
    const int* dstp = ei + E_EDGES;

    if (e0 + 3 < E_EDGES) {
        int4 d = *(const int4*)(dstp + e0);
        if (d.x >= lo && d.x < hi) perm[atomicAdd(offsets + d.x, 1)] = e0;
        if (d.y >= lo && d.y < hi) perm[atomicAdd(offsets + d.y, 1)] = e0 + 1;
        if (d.z >= lo && d.z < hi) perm[atomicAdd(offsets + d.z, 1)] = e0 + 2;
        if (d.w >= lo && d.w < hi) perm[atomicAdd(offsets + d.w, 1)] = e0 + 3;
    } else {
#pragma unroll
        for (int j = 0; j < 4; ++j) {
            int e = e0 + j;
            if (e < E_EDGES) {
                int dd = dstp[e];
                if (dd >= lo && dd < hi) perm[atomicAdd(offsets + dd, 1)] = e;
            }
        }
    }
}

// --- K4: gather (f16 x rows) + residual -> v[N][192] f16 --------------------
// one wave per node; lanes batch-fetch 64 edge records, then 4-wide
// shfl-broadcast inner loop with independent 128B x-row gathers.
__global__ __launch_bounds__(256) void k_gather(
    const int* __restrict__ perm, const int* __restrict__ endoff,
    const uint2* __restrict__ wbuf, const _Float16* __restrict__ xh,
    const float* __restrict__ x, const float* __restrict__ eps,
    _Float16* __restrict__ v)
{
    const int n    = blockIdx.x * 4 + (threadIdx.x >> 6);   // grid = N/4 exact
    const int lane = threadIdx.x & 63;

    const int start = (n == 0) ? 0 : endoff[n - 1];
    const int end   = endoff[n];

    float a0 = 0.f, a1 = 0.f, a2 = 0.f;
    float b0 = 0.f, b1 = 0.f, b2 = 0.f;
    float c0 = 0.f, c1 = 0.f, c2 = 0.f;
    float d0 = 0.f, d1 = 0.f, d2 = 0.f;

    for (int base = start; base < end; base += 64) {
        const int m = min(64, end - base);
        uint2 rec = make_uint2(0u, 0u);
        if (lane < m) {
            int p = perm[base + lane];     // coalesced 4B
            rec = wbuf[p];                 // random 8B, L2-resident
        }
        int j = 0;
        for (; j + 4 <= m; j += 4) {
            unsigned rxA = (unsigned)__shfl((int)rec.x, j);
            unsigned ryA = (unsigned)__shfl((int)rec.y, j);
            unsigned rxB = (unsigned)__shfl((int)rec.x, j + 1);
            unsigned ryB = (unsigned)__shfl((int)rec.y, j + 1);
            unsigned rxC = (unsigned)__shfl((int)rec.x, j + 2);
            unsigned ryC = (unsigned)__shfl((int)rec.y, j + 2);
            unsigned rxD = (unsigned)__shfl((int)rec.x, j + 3);
            unsigned ryD = (unsigned)__shfl((int)rec.y, j + 3);
            float xA = (float)xh[(size_t)(rxA & 0xFFFFu) * D_FEAT + lane];
            float xB = (float)xh[(size_t)(rxB & 0xFFFFu) * D_FEAT + lane];
            float xC = (float)xh[(size_t)(rxC & 0xFFFFu) * D_FEAT + lane];
            float xD = (float)xh[(size_t)(rxD & 0xFFFFu) * D_FEAT + lane];
            a0 = fmaf(h2f_bits(rxA >> 16),     xA, a0);
            a1 = fmaf(h2f_bits(ryA & 0xFFFFu), xA, a1);
            a2 = fmaf(h2f_bits(ryA >> 16),     xA, a2);
            b0 = fmaf(h2f_bits(rxB >> 16),     xB, b0);
            b1 = fmaf(h2f_bits(ryB & 0xFFFFu), xB, b1);
            b2 = fmaf(h2f_bits(ryB >> 16),     xB, b2);
            c0 = fmaf(h2f_bits(rxC >> 16),     xC, c0);
            c1 = fmaf(h2f_bits(ryC & 0xFFFFu), xC, c1);
            c2 = fmaf(h2f_bits(ryC >> 16),     xC, c2);
            d0 = fmaf(h2f_bits(rxD >> 16),     xD, d0);
            d1 = fmaf(h2f_bits(ryD & 0xFFFFu), xD, d1);
            d2 = fmaf(h2f_bits(ryD >> 16),     xD, d2);
        }
        for (; j < m; ++j) {
            unsigned rx0 = (unsigned)__shfl((int)rec.x, j);
            unsigned ry0 = (unsigned)__shfl((int)rec.y, j);
            float xa = (float)xh[(size_t)(rx0 & 0xFFFFu) * D_FEAT + lane];
            a0 = fmaf(h2f_bits(rx0 >> 16),     xa, a0);
            a1 = fmaf(h2f_bits(ry0 & 0xFFFFu), xa, a1);
            a2 = fmaf(h2f_bits(ry0 >> 16),     xa, a2);
        }
    }
    a0 += b0 + c0 + d0;
    a1 += b1 + c1 + d1;
    a2 += b2 + c2 + d2;

    float xn = x[(size_t)n * D_FEAT + lane];
    _Float16* vr = v + (size_t)n * CD;
    vr[lane]       = (_Float16)(a0 + (1.f + eps[0]) * xn);
    vr[64 + lane]  = (_Float16)(a1 + (1.f + eps[1]) * xn);
    vr[128 + lane] = (_Float16)(a2 + (1.f + eps[2]) * xn);
}

// --- K5: MLP1(lrelu) + MLP2 via f16 MFMA ------------------------------------
__global__ __launch_bounds__(256) void k_mlp(
    const _Float16* __restrict__ v,
    const float* __restrict__ nw1, const float* __restrict__ nb1,
    const float* __restrict__ nw2, const float* __restrict__ nb2,
    float* __restrict__ out)
{
    __shared__ _Float16 vtile[16][CD + 8];     // stride 400B (16B mult)
    __shared__ _Float16 htile[16][OUT_F + 8];  // stride 272B (16B mult)

    const int tid  = threadIdx.x;
    const int lane = tid & 63;
    const int wid  = tid >> 6;
    const int arow = lane & 15;
    const int kg   = lane >> 4;
    const int o0   = wid * 32;

    half8 w1f[6][2], w2f[4][2];
#pragma unroll
    for (int kk = 0; kk < 6; ++kk)
#pragma unroll
        for (int nt = 0; nt < 2; ++nt) {
            half8 f;
            int colb = o0 + nt * 16 + arow;
            int kb = kk * 32 + kg * 8;
#pragma unroll
            for (int j = 0; j < 8; ++j)
                f[j] = (_Float16)nw1[(size_t)(kb + j) * OUT_F + colb];
            w1f[kk][nt] = f;
        }
#pragma unroll
    for (int kk = 0; kk < 4; ++kk)
#pragma unroll
        for (int nt = 0; nt < 2; ++nt) {
            half8 f;
            int colb = o0 + nt * 16 + arow;
            int kb = kk * 32 + kg * 8;
#pragma unroll
            for (int j = 0; j < 8; ++j)
                f[j] = (_Float16)nw2[(size_t)(kb + j) * OUT_F + colb];
            w2f[kk][nt] = f;
        }

    const float b1a = nb1[o0 + arow],      b1b = nb1[o0 + 16 + arow];
    const float b2a = nb2[o0 + arow],      b2b = nb2[o0 + 16 + arow];

    for (int t = blockIdx.x; t < NTILES; t += gridDim.x) {
        const int nb16 = t * 16;
        __syncthreads();

        for (int i = tid; i < 16 * (CD / 8); i += 256) {    // 384 chunks
            int row = i / (CD / 8), c8 = i % (CD / 8);
            *(half8*)&vtile[row][c8 * 8] =
                *(const half8*)(v + (size_t)(nb16 + row) * CD + c8 * 8);
        }
        __syncthreads();

        f32x4 acc0 = {0.f, 0.f, 0.f, 0.f}, acc1 = {0.f, 0.f, 0.f, 0.f};
#pragma unroll
        for (int kk = 0; kk < 6; ++kk) {
            half8 a = *(const half8*)&vtile[arow][kk * 32 + kg * 8];
            acc0 = __builtin_amdgcn_mfma_f32_16x16x32_f16(a, w1f[kk][0], acc0, 0, 0, 0);
            acc1 = __builtin_amdgcn_mfma_f32_16x16x32_f16(a, w1f[kk][1], acc1, 0, 0, 0);
        }
#pragma unroll
        for (int r = 0; r < 4; ++r) {
            int hr = kg * 4 + r;
            htile[hr][o0 + arow]      = (_Float16)lrelu(acc0[r] + b1a);
            htile[hr][o0 + 16 + arow] = (_Float16)lrelu(acc1[r] + b1b);
        }
        __syncthreads();

        f32x4 c0 = {0.f, 0.f, 0.f, 0.f}, c1 = {0.f, 0.f, 0.f, 0.f};
#pragma unroll
        for (int kk = 0; kk < 4; ++kk) {
            half8 a = *(const half8*)&htile[arow][kk * 32 + kg * 8];
            c0 = __builtin_amdgcn_mfma_f32_16x16x32_f16(a, w2f[kk][0], c0, 0, 0, 0);
            c1 = __builtin_amdgcn_mfma_f32_16x16x32_f16(a, w2f[kk][1], c1, 0, 0, 0);
        }
#pragma unroll
        for (int r = 0; r < 4; ++r) {
            size_t n = (size_t)(nb16 + kg * 4 + r);
            out[n * OUT_F + o0 + arow]      = c0[r] + b2a;
            out[n * OUT_F + o0 + 16 + arow] = c1[r] + b2b;
        }
    }
}

extern "C" void kernel_launch(void* const* d_in, const int* in_sizes, int n_in,
                              void* d_out, int out_size, void* d_ws, size_t ws_size,
                              hipStream_t stream)
{
    const float* x    = (const float*)d_in[0];
    const int*   ei   = (const int*)  d_in[1];
    const float* ea   = (const float*)d_in[2];
    const float* w1   = (const float*)d_in[3];
    const float* b1   = (const float*)d_in[4];
    const float* w2   = (const float*)d_in[5];
    const float* b2   = (const float*)d_in[6];
    const float* eps  = (const float*)d_in[7];
    const float* nw1  = (const float*)d_in[8];
    const float* nb1  = (const float*)d_in[9];
    const float* nw2  = (const float*)d_in[10];
    const float* nb2  = (const float*)d_in[11];
    float* out = (float*)d_out;

    // workspace layout (total <= 38.4 MB, proven safe)
    char* ws = (char*)d_ws;
    int*       counts    = (int*)    (ws + 0);               // 200 KB
    int*       offsets   = (int*)    (ws + (256 << 10));     // 200 KB
    int*       blocksums = (int*)    (ws + (512 << 10));     // <1 KB
    int*       blockoffs = (int*)    (ws + (516 << 10));     // <1 KB
    int*       perm      = (int*)    (ws + (1u << 20));      // 3.2 MB
    _Float16*  xh        = (_Float16*)(ws + (5u << 20));     // 6.4 MB
    uint2*     wbuf      = (uint2*)  (ws + (12u << 20));     // 6.4 MB
    _Float16*  v         = (_Float16*)(ws + (19u << 20));    // 19.2 MB

    hipMemsetAsync(counts, 0, N_NODES * sizeof(int), stream);

    k_xcvt     <<<(N_NODES * D_FEAT / 4) / 256, 256, 0, stream>>>(x, xh);
    k_prep     <<<E_EDGES / 256,    256, 0, stream>>>(ei, ea, w1, b1, w2, b2, wbuf, counts);
    k_blocksum <<<NBLK_SCAN,        256, 0, stream>>>(counts, blocksums);
    k_scanblock<<<1,                256, 0, stream>>>(blocksums, blockoffs);
    k_scanfinal<<<NBLK_SCAN,        256, 0, stream>>>(counts, blockoffs, offsets);
    k_place    <<<PLACE_SLICES * 8, 256, 0, stream>>>(ei, offsets, perm);
    k_gather   <<<N_NODES / 4,      256, 0, stream>>>(perm, offsets, wbuf, xh, x, eps, v);
    k_mlp      <<<768,              256, 0, stream>>>(v, nw1, nb1, nw2, nb2, out);
}